// Round 5
// baseline (1011.486 us; speedup 1.0000x reference)
//
#include <hip/hip_runtime.h>
#include <hip/hip_bf16.h>

// ---------- types ----------
typedef __attribute__((ext_vector_type(8))) short short8;
typedef __attribute__((ext_vector_type(4))) float f32x4;

#define EMB 128
#define OUT 256
#define NRAD 6
#define NDENSE 3
#define CSR_NB 256   // blocks in fused CSR kernel (1 per CU -> co-resident)

static __device__ __forceinline__ unsigned short f32_to_bf16(float f) {
    union { float f; unsigned u; } v; v.f = f;
    unsigned r = v.u + 0x7fffu + ((v.u >> 16) & 1u);   // round-nearest-even
    return (unsigned short)(r >> 16);
}
static __device__ __forceinline__ float silu_f(float x) {
    return x / (1.f + __expf(-x));
}

// ---------- K0: init (zero counts/out/barrier, convert weights) ----------
__global__ __launch_bounds__(256) void init_kernel(
        int* __restrict__ bar, int* __restrict__ counts, float* __restrict__ out,
        const float* __restrict__ Wup, const float* __restrict__ Wd,
        unsigned short* __restrict__ Wbf, int N, int outn) {
    int i = blockIdx.x * blockDim.x + threadIdx.x;
    int stride = gridDim.x * blockDim.x;
    if (i == 0) *bar = 0;
    for (int j = i; j < N; j += stride) counts[j] = 0;
    for (int j = i; j < outn; j += stride) out[j] = 0.f;
    const int n1 = OUT * EMB, n2 = NDENSE * OUT * OUT;
    for (int j = i; j < n1 + n2; j += stride)
        Wbf[j] = f32_to_bf16(j < n1 ? Wup[j] : Wd[j - n1]);
}

// ---------- soft grid barrier (all CSR_NB blocks co-resident) ----------
static __device__ __forceinline__ void gsync(int* bar, int gen) {
    __syncthreads();
    if (threadIdx.x == 0) {
        __threadfence();   // make prior writes device-visible
        __hip_atomic_fetch_add(bar, 1, __ATOMIC_ACQ_REL, __HIP_MEMORY_SCOPE_AGENT);
        while (__hip_atomic_load(bar, __ATOMIC_ACQUIRE, __HIP_MEMORY_SCOPE_AGENT) < CSR_NB * gen)
            __builtin_amdgcn_s_sleep(1);
        __threadfence();
    }
    __syncthreads();
}

// ---------- K1: fused CSR build (hist -> scan -> scatter) ----------
__global__ __launch_bounds__(256) void csr_kernel(
        const int* __restrict__ src, int* __restrict__ counts, int* __restrict__ offsets,
        int* __restrict__ bsum, int* __restrict__ perm, int* __restrict__ bar, int E, int N) {
    const int t = threadIdx.x, b = blockIdx.x;
    const int gtid = b * 256 + t, gs = CSR_NB * 256;

    // phase 1: histogram
    for (int e = gtid; e < E; e += gs) atomicAdd(&counts[src[e]], 1);
    gsync(bar, 1);

    // phase 2: per-block chunk sums
    const int chunk = (N + CSR_NB - 1) / CSR_NB;   // 196 for N=50000 (<=256 assumed)
    __shared__ int sA[256], sB[256];
    int idx = b * chunk + t;
    int v = (t < chunk && idx < N)
          ? __hip_atomic_load(&counts[idx], __ATOMIC_ACQUIRE, __HIP_MEMORY_SCOPE_AGENT) : 0;
    sA[t] = v; __syncthreads();
    for (int d = 128; d > 0; d >>= 1) { if (t < d) sA[t] += sA[t + d]; __syncthreads(); }
    if (t == 0) __hip_atomic_store(&bsum[b], sA[0], __ATOMIC_RELEASE, __HIP_MEMORY_SCOPE_AGENT);
    gsync(bar, 2);

    // phase 3: redundant block-sum scan + chunk scan -> offsets
    int bs = __hip_atomic_load(&bsum[t], __ATOMIC_ACQUIRE, __HIP_MEMORY_SCOPE_AGENT);
    sB[t] = bs; __syncthreads();
    for (int d = 1; d < 256; d <<= 1) {
        int x = (t >= d) ? sB[t - d] : 0; __syncthreads();
        sB[t] += x; __syncthreads();
    }
    int bpre = (b == 0) ? 0 : sB[b - 1];
    if (b == 0 && t == 0) offsets[N] = sB[255];   // total == E (read by next kernel)
    sA[t] = v; __syncthreads();
    for (int d = 1; d < 256; d <<= 1) {
        int x = (t >= d) ? sA[t - d] : 0; __syncthreads();
        sA[t] += x; __syncthreads();
    }
    if (t < chunk && idx < N)
        __hip_atomic_store(&offsets[idx], bpre + sA[t] - v, __ATOMIC_RELEASE, __HIP_MEMORY_SCOPE_AGENT);
    gsync(bar, 3);

    // phase 4: scatter edge ids into CSR slots
    for (int e = gtid; e < E; e += gs) {
        int s = src[e];
        int cidx = atomicSub(&counts[s], 1) - 1;
        int o = __hip_atomic_load(&offsets[s], __ATOMIC_ACQUIRE, __HIP_MEMORY_SCOPE_AGENT);
        perm[o + cidx] = e;   // plain store; consumed by next kernel
    }
}

// ---------- K2: fused edge transform + per-node gather-sum (4-edge ILP) ----------
// IDENTICAL to R4 for attribution.
__global__ __launch_bounds__(256) void edge_accum_kernel(
        const float* __restrict__ m, const float* __restrict__ rbf,
        const int* __restrict__ perm, const int* __restrict__ offsets,
        const float* __restrict__ W_rbf, unsigned* __restrict__ t_pack, int N) {
    const int lane = threadIdx.x & 63;
    const int gw = blockIdx.x * (blockDim.x >> 6) + (threadIdx.x >> 6);
    const int nwaves = gridDim.x * (blockDim.x >> 6);

    const float* wr = W_rbf + lane * 2 * NRAD;
    const float wa0 = wr[0], wa1 = wr[1], wa2 = wr[2], wa3 = wr[3], wa4 = wr[4], wa5 = wr[5];
    const float wb0 = wr[6], wb1 = wr[7], wb2 = wr[8], wb3 = wr[9], wb4 = wr[10], wb5 = wr[11];

    for (int node = gw; node < N; node += nwaves) {
        int beg = offsets[node], end = offsets[node + 1];
        float ax = 0.f, ay = 0.f;
        for (int i = beg; i < end; i += 4) {
            int rem = end - i;
            int i1 = (rem > 1) ? i + 1 : i;
            int i2 = (rem > 2) ? i + 2 : i;
            int i3 = (rem > 3) ? i + 3 : i;
            int e0 = perm[i], e1 = perm[i1], e2 = perm[i2], e3 = perm[i3];
            const float2* rp0 = (const float2*)(rbf + (size_t)e0 * NRAD);
            const float2* rp1 = (const float2*)(rbf + (size_t)e1 * NRAD);
            const float2* rp2 = (const float2*)(rbf + (size_t)e2 * NRAD);
            const float2* rp3 = (const float2*)(rbf + (size_t)e3 * NRAD);
            float2 q00 = rp0[0], q01 = rp0[1], q02 = rp0[2];
            float2 q10 = rp1[0], q11 = rp1[1], q12 = rp1[2];
            float2 q20 = rp2[0], q21 = rp2[1], q22 = rp2[2];
            float2 q30 = rp3[0], q31 = rp3[1], q32 = rp3[2];
            const float2 m0 = *(const float2*)(m + (size_t)e0 * EMB + 2 * lane);
            const float2 m1 = *(const float2*)(m + (size_t)e1 * EMB + 2 * lane);
            const float2 m2 = *(const float2*)(m + (size_t)e2 * EMB + 2 * lane);
            const float2 m3 = *(const float2*)(m + (size_t)e3 * EMB + 2 * lane);
            float g1 = (rem > 1) ? 1.f : 0.f;
            float g2 = (rem > 2) ? 1.f : 0.f;
            float g3 = (rem > 3) ? 1.f : 0.f;
            float pa0 = wa0*q00.x + wa1*q00.y + wa2*q01.x + wa3*q01.y + wa4*q02.x + wa5*q02.y;
            float pb0 = wb0*q00.x + wb1*q00.y + wb2*q01.x + wb3*q01.y + wb4*q02.x + wb5*q02.y;
            float pa1 = (wa0*q10.x + wa1*q10.y + wa2*q11.x + wa3*q11.y + wa4*q12.x + wa5*q12.y) * g1;
            float pb1 = (wb0*q10.x + wb1*q10.y + wb2*q11.x + wb3*q11.y + wb4*q12.x + wb5*q12.y) * g1;
            float pa2 = (wa0*q20.x + wa1*q20.y + wa2*q21.x + wa3*q21.y + wa4*q22.x + wa5*q22.y) * g2;
            float pb2 = (wb0*q20.x + wb1*q20.y + wb2*q21.x + wb3*q21.y + wb4*q22.x + wb5*q22.y) * g2;
            float pa3 = (wa0*q30.x + wa1*q30.y + wa2*q31.x + wa3*q31.y + wa4*q32.x + wa5*q32.y) * g3;
            float pb3 = (wb0*q30.x + wb1*q30.y + wb2*q31.x + wb3*q31.y + wb4*q32.x + wb5*q32.y) * g3;
            ax = fmaf(m0.x, pa0, ax); ay = fmaf(m0.y, pb0, ay);
            ax = fmaf(m1.x, pa1, ax); ay = fmaf(m1.y, pb1, ay);
            ax = fmaf(m2.x, pa2, ax); ay = fmaf(m2.y, pb2, ay);
            ax = fmaf(m3.x, pa3, ax); ay = fmaf(m3.y, pb3, ay);
        }
        unsigned short hx = f32_to_bf16(ax), hy = f32_to_bf16(ay);
        t_pack[(size_t)node * 64 + lane] = (unsigned)hx | ((unsigned)hy << 16);
    }
}

// ---------- K3: fused MLP (up-proj + 3x dense+silu) + per-graph readout ----------
// Block = 4 waves x 16 rows; wave-local LDS staging with XOR swizzle.
// Final layer: in-register row-reduction + atomicAdd into out[graph] (gids sorted).
__global__ __launch_bounds__(256) void fused_mlp_kernel(
        const unsigned short* __restrict__ A0,    // [M,128] bf16
        const unsigned short* __restrict__ Wup,   // [256,128] bf16
        const unsigned short* __restrict__ Wd,    // [3,256,256] bf16
        const float* __restrict__ bd,             // [3,256]
        const int* __restrict__ gids,             // [M] sorted
        float* __restrict__ out, int M) {
    __shared__ unsigned short smem[4][16 * 256];
    const int w    = threadIdx.x >> 6;
    const int lane = threadIdx.x & 63;
    const int r    = lane & 15;
    const int kg   = lane >> 4;          // khalf / row-group
    const int row0 = blockIdx.x * 64 + w * 16;
    char* swc = (char*)&smem[w][0];

    f32x4 acc[16];
#pragma unroll
    for (int i = 0; i < 16; ++i) acc[i] = (f32x4){0.f, 0.f, 0.f, 0.f};

    // ---- layer 0: up-projection, K=128, A from global ----
    const int arow = row0 + r;
    const bool rowok = (arow < M);
    const unsigned short* Arow = A0 + (size_t)arow * EMB;
#pragma unroll
    for (int ks = 0; ks < EMB; ks += 32) {
        int ka = ks + kg * 8;
        short8 afrag;
        if (rowok) afrag = *(const short8*)(Arow + ka);
        else       afrag = (short8){0,0,0,0,0,0,0,0};
#pragma unroll
        for (int ct = 0; ct < 16; ++ct) {
            int col = ct * 16 + r;
            short8 bfrag = *(const short8*)(Wup + (size_t)col * EMB + ka);
            acc[ct] = __builtin_amdgcn_mfma_f32_16x16x32_bf16(afrag, bfrag, acc[ct], 0, 0, 0);
        }
    }

    // stash layer-0 output into LDS (XOR swizzle byte ^= (row&7)<<4)
#pragma unroll
    for (int ct = 0; ct < 16; ++ct) {
        int col = ct * 16 + r;
#pragma unroll
        for (int reg = 0; reg < 4; ++reg) {
            int rw = 4 * kg + reg;
            int byte = rw * 512 + col * 2;
            byte ^= (rw & 7) << 4;
            *(unsigned short*)(swc + byte) = f32_to_bf16(acc[ct][reg]);
        }
    }
    __syncthreads();

    // ---- layers 1..3: dense 256x256 + bias + silu ----
    for (int ell = 0; ell < NDENSE; ++ell) {
        const unsigned short* Bl = Wd + (size_t)ell * OUT * OUT;
        const float* bias = bd + ell * OUT;
#pragma unroll
        for (int i = 0; i < 16; ++i) acc[i] = (f32x4){0.f, 0.f, 0.f, 0.f};
#pragma unroll
        for (int ks = 0; ks < 8; ++ks) {
            int byte = r * 512 + ks * 64 + kg * 16;
            byte ^= (r & 7) << 4;
            short8 afrag = *(const short8*)(swc + byte);
            int ka = ks * 32 + kg * 8;
#pragma unroll
            for (int ct = 0; ct < 16; ++ct) {
                int col = ct * 16 + r;
                short8 bfrag = *(const short8*)(Bl + (size_t)col * OUT + ka);
                acc[ct] = __builtin_amdgcn_mfma_f32_16x16x32_bf16(afrag, bfrag, acc[ct], 0, 0, 0);
            }
        }
        if (ell < NDENSE - 1) {
            __syncthreads();
#pragma unroll
            for (int ct = 0; ct < 16; ++ct) {
                int col = ct * 16 + r;
                float b = bias[col];
#pragma unroll
                for (int reg = 0; reg < 4; ++reg) {
                    int rw = 4 * kg + reg;
                    int byte = rw * 512 + col * 2;
                    byte ^= (rw & 7) << 4;
                    *(unsigned short*)(swc + byte) = f32_to_bf16(silu_f(acc[ct][reg] + b));
                }
            }
            __syncthreads();
        } else {
            // ---- final layer: silu + per-graph reduction, atomicAdd into out ----
            bool fast = (row0 + 15 < M) && (gids[row0] == gids[row0 + 15]);
            if (fast) {
                int gph = gids[row0];
                float* og = out + (size_t)gph * OUT;
#pragma unroll
                for (int ct = 0; ct < 16; ++ct) {
                    int col = ct * 16 + r;
                    float b = bias[col];
                    float v = silu_f(acc[ct][0] + b) + silu_f(acc[ct][1] + b)
                            + silu_f(acc[ct][2] + b) + silu_f(acc[ct][3] + b);
                    v += __shfl_xor(v, 16);
                    v += __shfl_xor(v, 32);
                    if (lane < 16) atomicAdd(&og[col], v);
                }
            } else {
                int g4[4];
#pragma unroll
                for (int reg = 0; reg < 4; ++reg) {
                    int orow = row0 + kg * 4 + reg;
                    g4[reg] = (orow < M) ? gids[orow] : -1;
                }
#pragma unroll
                for (int ct = 0; ct < 16; ++ct) {
                    int col = ct * 16 + r;
                    float b = bias[col];
#pragma unroll
                    for (int reg = 0; reg < 4; ++reg)
                        if (g4[reg] >= 0)
                            atomicAdd(&out[(size_t)g4[reg] * OUT + col],
                                      silu_f(acc[ct][reg] + b));
                }
            }
        }
    }
}

// ---------- host ----------
extern "C" void kernel_launch(void* const* d_in, const int* in_sizes, int n_in,
                              void* d_out, int out_size, void* d_ws, size_t ws_size,
                              hipStream_t stream) {
    const float* m         = (const float*)d_in[0];
    const float* rbf       = (const float*)d_in[1];
    const int*   src       = (const int*)d_in[2];
    const int*   gids      = (const int*)d_in[3];
    const float* W_rbf     = (const float*)d_in[4];
    const float* W_up      = (const float*)d_in[5];
    const float* W_dense   = (const float*)d_in[6];
    const float* b_dense   = (const float*)d_in[7];
    float* out = (float*)d_out;

    const int E = in_sizes[2];
    const int N = in_sizes[3];

    size_t off = 0;
    auto alloc = [&](size_t bytes) -> void* {
        void* p = (char*)d_ws + off;
        off += (bytes + 255) & ~(size_t)255;
        return p;
    };
    int* bar     = (int*)alloc(256);
    int* counts  = (int*)alloc((size_t)N * 4);
    int* offsets = (int*)alloc(((size_t)N + 1) * 4);
    int* bsum    = (int*)alloc(CSR_NB * 4);
    int* perm    = (int*)alloc((size_t)E * 4);
    unsigned short* t_bf = (unsigned short*)alloc((size_t)N * EMB * 2);
    unsigned short* Wbf  = (unsigned short*)alloc((size_t)(OUT * EMB + NDENSE * OUT * OUT) * 2);
    unsigned short* Wup_bf = Wbf;
    unsigned short* Wd_bf  = Wbf + OUT * EMB;

    // K0: init (zero counts/out/bar, convert weights)
    init_kernel<<<256, 256, 0, stream>>>(bar, counts, out, W_up, W_dense, Wbf, N, out_size);

    // K1: fused CSR build (hist + scan + scatter, soft grid barrier)
    csr_kernel<<<CSR_NB, 256, 0, stream>>>(src, counts, offsets, bsum, perm, bar, E, N);

    // K2: edge transform + node gather (identical to R4)
    edge_accum_kernel<<<2048, 256, 0, stream>>>(m, rbf, perm, offsets, W_rbf,
                                                (unsigned*)t_bf, N);

    // K3: fused MLP + per-graph readout
    fused_mlp_kernel<<<(N + 63) / 64, 256, 0, stream>>>(t_bf, Wup_bf, Wd_bf, b_dense,
                                                        gids, out, N);
}